// Round 22
// baseline (165.264 us; speedup 1.0000x reference)
//
#include <hip/hip_runtime.h>

#define B_    16
#define T_    4096
#define D_    1024
#define CD_   8
#define CS_   1024
#define NROWS 65536
#define EPSF  1e-12f

// ---- d_out float offsets ----
#define OUT_OFF    0
#define COMMIT_OFF 67108864
#define CBLOSS_OFF 67108880
#define IDX_OFF    67108896
#define ZE_OFF     67174432

// ---- ws float offsets ----
#define WS_INWT 0
#define WS_CBR  8192
#define WS_OUTW 16384
#define WS_CN2  24576

template <int CTRL>
static __device__ __forceinline__ float dpp_add(float x) {
    int xi = __builtin_bit_cast(int, x);
    int yi = __builtin_amdgcn_update_dpp(xi, xi, CTRL, 0xF, 0xF, false);
    return x + __builtin_bit_cast(float, yi);
}

// ---------------------------------------------------------------------------
// Prep, 24 blocks x 256 (verbatim)
// ---------------------------------------------------------------------------
__global__ __launch_bounds__(256)
void vq_prep(const float* __restrict__ in_v, const float* __restrict__ in_g,
             const float* __restrict__ out_v, const float* __restrict__ out_g,
             const float* __restrict__ cb, float* __restrict__ ws,
             float* __restrict__ dout) {
    int t = threadIdx.x;
    int blk = blockIdx.x;

    if (blk < 16) {
        __shared__ float s_norm[CD_];
        int lane = t & 63;
        int wid = t >> 6;
        #pragma unroll
        for (int half = 0; half < 2; ++half) {
            int c = wid + half * 4;
            float s = 0.f;
            #pragma unroll
            for (int i = 0; i < D_ / 64; ++i) {
                float v = in_v[(size_t)(lane + 64 * i) * CD_ + c];
                s = fmaf(v, v, s);
            }
            #pragma unroll
            for (int m = 1; m <= 32; m <<= 1) s += __shfl_xor(s, m, 64);
            if (lane == 0) s_norm[c] = sqrtf(s);
        }
        __syncthreads();

        #pragma unroll
        for (int rep = 0; rep < 2; ++rep) {
            int idx = blk * 512 + rep * 256 + t;
            int c = idx >> 10, d = idx & (D_ - 1);
            ws[WS_INWT + idx] = in_g[c] * in_v[(size_t)d * CD_ + c] / fmaxf(EPSF, s_norm[c]);
        }

        if (blk == 0 && t < 32) dout[COMMIT_OFF + t] = 0.f;
    } else if (blk < 20) {
        int j = (blk - 16) * 256 + t;
        float v[CD_]; float s = 0.f;
        #pragma unroll
        for (int c = 0; c < CD_; ++c) { v[c] = cb[j * CD_ + c]; s = fmaf(v[c], v[c], s); }
        float n = fmaxf(EPSF, sqrtf(s));
        float n2 = 0.f;
        #pragma unroll
        for (int c = 0; c < CD_; ++c) {
            float q = v[c] / n;
            ws[WS_CBR + j * CD_ + c] = q;
            n2 = fmaf(q, q, n2);
        }
        ws[WS_CN2 + j] = n2;
    } else {
        int d = (blk - 20) * 256 + t;
        float v[CD_]; float s = 0.f;
        #pragma unroll
        for (int c = 0; c < CD_; ++c) { v[c] = out_v[c * D_ + d]; s = fmaf(v[c], v[c], s); }
        float n = fmaxf(EPSF, sqrtf(s));
        float g = out_g[d];
        #pragma unroll
        for (int c = 0; c < CD_; ++c) ws[WS_OUTW + c * D_ + d] = g * v[c] / n;
    }
}

// ---------------------------------------------------------------------------
// Fused ze -> scan -> out (R19 bodies verbatim), 2048 blocks x 256 threads,
// 32 rows/block: same 4 blocks/CU, half-length phases -> finer read/write
// phase mosaic across co-resident blocks.
// ---------------------------------------------------------------------------
__global__ __launch_bounds__(256)
void vq_fused(const float* __restrict__ z, const float* __restrict__ in_b,
              const float* __restrict__ cb, const float* __restrict__ ws,
              const float* __restrict__ out_b, float* __restrict__ dout) {
    __shared__ float s_cb[CS_ * CD_];  // 32 KB
    __shared__ float s_c2[CS_];        // 4 KB
    __shared__ float s_ze[32 * CD_];   // 1 KB
    __shared__ int   s_idx[32];
    __shared__ float s_loss[4];
    int t = threadIdx.x;
    int lane = t & 63;
    int wid = t >> 6;
    int base = blockIdx.x * 32;

    // ---- stage codebook (consumed after the ze-phase barrier) ----
    #pragma unroll
    for (int i = 0; i < 8; ++i)
        ((float4*)s_cb)[i * 256 + t] = ((const float4*)(ws + WS_CBR))[i * 256 + t];
    ((float4*)s_c2)[t] = ((const float4*)(ws + WS_CN2))[t];

    // ================= ze phase (R19-exact) =================
    {
        float4 w[CD_][4];
        #pragma unroll
        for (int c = 0; c < CD_; ++c)
            #pragma unroll
            for (int k = 0; k < 4; ++k)
                w[c][k] = *(const float4*)(ws + WS_INWT + c * D_ + (k << 8) + (lane << 2));

        float bia[CD_];
        #pragma unroll
        for (int c = 0; c < CD_; ++c) bia[c] = in_b[c];

        for (int itz = 0; itz < 4; ++itz) {
            int lrow = itz * 8 + wid * 2;
            int row0 = base + lrow;

            float2 acc[2][CD_];
            #pragma unroll
            for (int r = 0; r < 2; ++r)
                #pragma unroll
                for (int c = 0; c < CD_; ++c) acc[r][c] = make_float2(0.f, 0.f);

            #pragma unroll
            for (int k = 0; k < 4; ++k) {
                float4 zv0 = *(const float4*)(z + (size_t)(row0)     * D_ + (k << 8) + (lane << 2));
                float4 zv1 = *(const float4*)(z + (size_t)(row0 + 1) * D_ + (k << 8) + (lane << 2));
                #pragma unroll
                for (int c = 0; c < CD_; ++c) {
                    acc[0][c].x = fmaf(zv0.x, w[c][k].x, acc[0][c].x);
                    acc[0][c].y = fmaf(zv0.y, w[c][k].y, acc[0][c].y);
                    acc[0][c].x = fmaf(zv0.z, w[c][k].z, acc[0][c].x);
                    acc[0][c].y = fmaf(zv0.w, w[c][k].w, acc[0][c].y);
                    acc[1][c].x = fmaf(zv1.x, w[c][k].x, acc[1][c].x);
                    acc[1][c].y = fmaf(zv1.y, w[c][k].y, acc[1][c].y);
                    acc[1][c].x = fmaf(zv1.z, w[c][k].z, acc[1][c].x);
                    acc[1][c].y = fmaf(zv1.w, w[c][k].w, acc[1][c].y);
                }
            }

            float ze[2][CD_];
            #pragma unroll
            for (int r = 0; r < 2; ++r) {
                #pragma unroll
                for (int c = 0; c < CD_; ++c) {
                    float v = acc[r][c].x + acc[r][c].y;
                    v = dpp_add<0xB1>(v);    // + lane^1
                    v = dpp_add<0x4E>(v);    // + lane^2
                    v = dpp_add<0x124>(v);   // + lane+4 (row_ror:4)
                    v = dpp_add<0x128>(v);   // + lane+8 (row_ror:8)
                    v += __shfl_xor(v, 16, 64);
                    v += __shfl_xor(v, 32, 64);
                    ze[r][c] = v + bia[c];
                }
            }

            if (lane == 0) {
                float4 p0 = make_float4(ze[0][0], ze[0][1], ze[0][2], ze[0][3]);
                float4 p1 = make_float4(ze[0][4], ze[0][5], ze[0][6], ze[0][7]);
                *(float4*)(dout + ZE_OFF + (size_t)row0 * CD_)     = p0;
                *(float4*)(dout + ZE_OFF + (size_t)row0 * CD_ + 4) = p1;
                *(float4*)(s_ze + lrow * CD_)     = p0;
                *(float4*)(s_ze + lrow * CD_ + 4) = p1;
            }
            if (lane == 1) {
                float4 p0 = make_float4(ze[1][0], ze[1][1], ze[1][2], ze[1][3]);
                float4 p1 = make_float4(ze[1][4], ze[1][5], ze[1][6], ze[1][7]);
                *(float4*)(dout + ZE_OFF + (size_t)(row0 + 1) * CD_)     = p0;
                *(float4*)(dout + ZE_OFF + (size_t)(row0 + 1) * CD_ + 4) = p1;
                *(float4*)(s_ze + (lrow + 1) * CD_)     = p0;
                *(float4*)(s_ze + (lrow + 1) * CD_ + 4) = p1;
            }
        }
    }
    __syncthreads();

    // ========== scan phase (R19-exact per row; 1 row/slot, 8 subs) ========
    {
        int slot = t >> 3;        // 0..31
        int sub = t & 7;
        int lrow = slot;
        int row = base + lrow;

        float4 a  = *(const float4*)(s_ze + lrow * CD_);
        float4 b4 = *(const float4*)(s_ze + lrow * CD_ + 4);
        float s = 0.f;
        s = fmaf(a.x, a.x, s);   s = fmaf(a.y, a.y, s);
        s = fmaf(a.z, a.z, s);   s = fmaf(a.w, a.w, s);
        s = fmaf(b4.x, b4.x, s); s = fmaf(b4.y, b4.y, s);
        s = fmaf(b4.z, b4.z, s); s = fmaf(b4.w, b4.w, s);
        float tw = 2.f / fmaxf(EPSF, sqrtf(s));

        float bs = -1e38f;
        int bj = 0;
        #pragma unroll 2
        for (int jj = 0; jj < 128; ++jj) {
            int j = (jj << 3) + sub;
            float4 ca  = ((const float4*)s_cb)[j * 2];
            float4 cbv = ((const float4*)s_cb)[j * 2 + 1];
            float c2 = s_c2[j];
            float2 dp = make_float2(0.f, 0.f);
            dp.x = fmaf(ca.x,  a.x,  dp.x);
            dp.y = fmaf(ca.y,  a.y,  dp.y);
            dp.x = fmaf(ca.z,  a.z,  dp.x);
            dp.y = fmaf(ca.w,  a.w,  dp.y);
            dp.x = fmaf(cbv.x, b4.x, dp.x);
            dp.y = fmaf(cbv.y, b4.y, dp.y);
            dp.x = fmaf(cbv.z, b4.z, dp.x);
            dp.y = fmaf(cbv.w, b4.w, dp.y);
            float dot = dp.x + dp.y;
            float sc = fmaf(dot, tw, -c2);
            if (sc > bs || (sc == bs && j < bj)) { bs = sc; bj = j; }
        }

        #pragma unroll
        for (int m = 1; m <= 4; m <<= 1) {
            float os = __shfl_xor(bs, m, 64);
            int   oj = __shfl_xor(bj, m, 64);
            bool take = (os > bs) || (os == bs && oj < bj);
            bs = take ? os : bs;
            bj = take ? oj : bj;
        }

        float lsum = 0.f;
        if (sub == 0) {
            dout[IDX_OFF + row] = (float)bj;
            s_idx[lrow] = bj;
            const float* q = cb + (size_t)bj * CD_;
            float d0 = a.x  - q[0]; lsum = fmaf(d0, d0, lsum);
            float d1 = a.y  - q[1]; lsum = fmaf(d1, d1, lsum);
            float d2 = a.z  - q[2]; lsum = fmaf(d2, d2, lsum);
            float d3 = a.w  - q[3]; lsum = fmaf(d3, d3, lsum);
            float d4 = b4.x - q[4]; lsum = fmaf(d4, d4, lsum);
            float d5 = b4.y - q[5]; lsum = fmaf(d5, d5, lsum);
            float d6 = b4.z - q[6]; lsum = fmaf(d6, d6, lsum);
            float d7 = b4.w - q[7]; lsum = fmaf(d7, d7, lsum);
        }
        lsum += __shfl_xor(lsum, 1, 64);
        lsum += __shfl_xor(lsum, 2, 64);
        lsum += __shfl_xor(lsum, 4, 64);
        lsum += __shfl_xor(lsum, 8, 64);
        lsum += __shfl_xor(lsum, 16, 64);
        lsum += __shfl_xor(lsum, 32, 64);
        if (lane == 0) s_loss[wid] = lsum;
    }
    __syncthreads();
    if (t == 0) {
        float tot = s_loss[0] + s_loss[1] + s_loss[2] + s_loss[3];
        float v = tot * (1.f / 32768.f);
        int bt = base >> 12;
        atomicAdd(dout + COMMIT_OFF + bt, v);
        atomicAdd(dout + CBLOSS_OFF + bt, v);
    }

    // keep out-phase weight loads from hoisting into the ze phase
    __builtin_amdgcn_sched_barrier(0);

    // ================= out phase (R19-exact) =================
    {
        float4 w[CD_][4];
        #pragma unroll
        for (int c = 0; c < CD_; ++c)
            #pragma unroll
            for (int k = 0; k < 4; ++k)
                w[c][k] = *(const float4*)(ws + WS_OUTW + c * D_ + (k << 8) + (lane << 2));

        float4 ob[4];
        #pragma unroll
        for (int k = 0; k < 4; ++k)
            ob[k] = *(const float4*)(out_b + (k << 8) + (lane << 2));

        #pragma unroll
        for (int itr = 0; itr < 2; ++itr) {
            int lr0 = (wid << 3) + (itr << 2);     // wave wid: rows wid*8 .. +7
            int row0 = base + lr0;

            float zq[4][CD_];
            #pragma unroll
            for (int r = 0; r < 4; ++r) {
                int j = s_idx[lr0 + r];
                #pragma unroll
                for (int c = 0; c < CD_; ++c) zq[r][c] = cb[j * CD_ + c];
            }

            #pragma unroll
            for (int k = 0; k < 4; ++k) {
                float4 a0 = ob[k], a1 = ob[k], a2 = ob[k], a3 = ob[k];
                #pragma unroll
                for (int c = 0; c < CD_; ++c) {
                    a0.x = fmaf(zq[0][c], w[c][k].x, a0.x); a0.y = fmaf(zq[0][c], w[c][k].y, a0.y);
                    a0.z = fmaf(zq[0][c], w[c][k].z, a0.z); a0.w = fmaf(zq[0][c], w[c][k].w, a0.w);
                    a1.x = fmaf(zq[1][c], w[c][k].x, a1.x); a1.y = fmaf(zq[1][c], w[c][k].y, a1.y);
                    a1.z = fmaf(zq[1][c], w[c][k].z, a1.z); a1.w = fmaf(zq[1][c], w[c][k].w, a1.w);
                    a2.x = fmaf(zq[2][c], w[c][k].x, a2.x); a2.y = fmaf(zq[2][c], w[c][k].y, a2.y);
                    a2.z = fmaf(zq[2][c], w[c][k].z, a2.z); a2.w = fmaf(zq[2][c], w[c][k].w, a2.w);
                    a3.x = fmaf(zq[3][c], w[c][k].x, a3.x); a3.y = fmaf(zq[3][c], w[c][k].y, a3.y);
                    a3.z = fmaf(zq[3][c], w[c][k].z, a3.z); a3.w = fmaf(zq[3][c], w[c][k].w, a3.w);
                }
                size_t baddr = (size_t)row0 * D_ + (k << 8) + (lane << 2);
                *(float4*)(dout + OUT_OFF + baddr)           = a0;
                *(float4*)(dout + OUT_OFF + baddr + D_)      = a1;
                *(float4*)(dout + OUT_OFF + baddr + 2 * D_)  = a2;
                *(float4*)(dout + OUT_OFF + baddr + 3 * D_)  = a3;
            }
        }
    }
}

extern "C" void kernel_launch(void* const* d_in, const int* in_sizes, int n_in,
                              void* d_out, int out_size, void* d_ws, size_t ws_size,
                              hipStream_t stream) {
    const float* z     = (const float*)d_in[0];
    const float* in_v  = (const float*)d_in[1];
    const float* in_g  = (const float*)d_in[2];
    const float* in_b  = (const float*)d_in[3];
    const float* out_v = (const float*)d_in[4];
    const float* out_g = (const float*)d_in[5];
    const float* out_b = (const float*)d_in[6];
    const float* cb    = (const float*)d_in[7];
    float* dout = (float*)d_out;
    float* ws   = (float*)d_ws;

    vq_prep<<<24, 256, 0, stream>>>(in_v, in_g, out_v, out_g, cb, ws, dout);
    vq_fused<<<2048, 256, 0, stream>>>(z, in_b, cb, ws, out_b, dout);
}

// Round 24
// 139.561 us; speedup vs baseline: 1.1842x; 1.1842x over previous
//
#include <hip/hip_runtime.h>

#define B_    16
#define T_    4096
#define D_    1024
#define CD_   8
#define CS_   1024
#define NROWS 65536
#define EPSF  1e-12f

// ---- d_out float offsets ----
#define OUT_OFF    0
#define COMMIT_OFF 67108864
#define CBLOSS_OFF 67108880
#define IDX_OFF    67108896
#define ZE_OFF     67174432

// ---- ws float offsets ----
#define WS_INWT 0
#define WS_CBR  8192
#define WS_OUTW 16384
#define WS_CN2  24576

template <int CTRL>
static __device__ __forceinline__ float dpp_add(float x) {
    int xi = __builtin_bit_cast(int, x);
    int yi = __builtin_amdgcn_update_dpp(xi, xi, CTRL, 0xF, 0xF, false);
    return x + __builtin_bit_cast(float, yi);
}

// ---------------------------------------------------------------------------
// Prep, 24 blocks x 256 (R19 verbatim)
// ---------------------------------------------------------------------------
__global__ __launch_bounds__(256)
void vq_prep(const float* __restrict__ in_v, const float* __restrict__ in_g,
             const float* __restrict__ out_v, const float* __restrict__ out_g,
             const float* __restrict__ cb, float* __restrict__ ws,
             float* __restrict__ dout) {
    int t = threadIdx.x;
    int blk = blockIdx.x;

    if (blk < 16) {
        __shared__ float s_norm[CD_];
        int lane = t & 63;
        int wid = t >> 6;
        #pragma unroll
        for (int half = 0; half < 2; ++half) {
            int c = wid + half * 4;
            float s = 0.f;
            #pragma unroll
            for (int i = 0; i < D_ / 64; ++i) {
                float v = in_v[(size_t)(lane + 64 * i) * CD_ + c];
                s = fmaf(v, v, s);
            }
            #pragma unroll
            for (int m = 1; m <= 32; m <<= 1) s += __shfl_xor(s, m, 64);
            if (lane == 0) s_norm[c] = sqrtf(s);
        }
        __syncthreads();

        #pragma unroll
        for (int rep = 0; rep < 2; ++rep) {
            int idx = blk * 512 + rep * 256 + t;
            int c = idx >> 10, d = idx & (D_ - 1);
            ws[WS_INWT + idx] = in_g[c] * in_v[(size_t)d * CD_ + c] / fmaxf(EPSF, s_norm[c]);
        }

        if (blk == 0 && t < 32) dout[COMMIT_OFF + t] = 0.f;
    } else if (blk < 20) {
        int j = (blk - 16) * 256 + t;
        float v[CD_]; float s = 0.f;
        #pragma unroll
        for (int c = 0; c < CD_; ++c) { v[c] = cb[j * CD_ + c]; s = fmaf(v[c], v[c], s); }
        float n = fmaxf(EPSF, sqrtf(s));
        float n2 = 0.f;
        #pragma unroll
        for (int c = 0; c < CD_; ++c) {
            float q = v[c] / n;
            ws[WS_CBR + j * CD_ + c] = q;
            n2 = fmaf(q, q, n2);
        }
        ws[WS_CN2 + j] = n2;
    } else {
        int d = (blk - 20) * 256 + t;
        float v[CD_]; float s = 0.f;
        #pragma unroll
        for (int c = 0; c < CD_; ++c) { v[c] = out_v[c * D_ + d]; s = fmaf(v[c], v[c], s); }
        float n = fmaxf(EPSF, sqrtf(s));
        float g = out_g[d];
        #pragma unroll
        for (int c = 0; c < CD_; ++c) ws[WS_OUTW + c * D_ + d] = g * v[c] / n;
    }
}

// ---------------------------------------------------------------------------
// Fused ze -> scan -> out (R19 verbatim), 1024 blocks x 256 threads,
// 64 rows/block: ~4 co-resident blocks/CU for read/write phase interleave.
// ---------------------------------------------------------------------------
__global__ __launch_bounds__(256)
void vq_fused(const float* __restrict__ z, const float* __restrict__ in_b,
              const float* __restrict__ cb, const float* __restrict__ ws,
              const float* __restrict__ out_b, float* __restrict__ dout) {
    __shared__ float s_cb[CS_ * CD_];  // 32 KB
    __shared__ float s_c2[CS_];        // 4 KB
    __shared__ float s_ze[64 * CD_];   // 2 KB
    __shared__ int   s_idx[64];
    __shared__ float s_loss[4];
    int t = threadIdx.x;
    int lane = t & 63;
    int wid = t >> 6;
    int base = blockIdx.x * 64;

    // ---- stage codebook (consumed after the ze-phase barrier) ----
    #pragma unroll
    for (int i = 0; i < 8; ++i)
        ((float4*)s_cb)[i * 256 + t] = ((const float4*)(ws + WS_CBR))[i * 256 + t];
    ((float4*)s_c2)[t] = ((const float4*)(ws + WS_CN2))[t];

    // ================= ze phase =================
    {
        float4 w[CD_][4];
        #pragma unroll
        for (int c = 0; c < CD_; ++c)
            #pragma unroll
            for (int k = 0; k < 4; ++k)
                w[c][k] = *(const float4*)(ws + WS_INWT + c * D_ + (k << 8) + (lane << 2));

        float bia[CD_];
        #pragma unroll
        for (int c = 0; c < CD_; ++c) bia[c] = in_b[c];

        for (int itz = 0; itz < 8; ++itz) {
            int lrow = itz * 8 + wid * 2;
            int row0 = base + lrow;

            float2 acc[2][CD_];
            #pragma unroll
            for (int r = 0; r < 2; ++r)
                #pragma unroll
                for (int c = 0; c < CD_; ++c) acc[r][c] = make_float2(0.f, 0.f);

            #pragma unroll
            for (int k = 0; k < 4; ++k) {
                float4 zv0 = *(const float4*)(z + (size_t)(row0)     * D_ + (k << 8) + (lane << 2));
                float4 zv1 = *(const float4*)(z + (size_t)(row0 + 1) * D_ + (k << 8) + (lane << 2));
                #pragma unroll
                for (int c = 0; c < CD_; ++c) {
                    acc[0][c].x = fmaf(zv0.x, w[c][k].x, acc[0][c].x);
                    acc[0][c].y = fmaf(zv0.y, w[c][k].y, acc[0][c].y);
                    acc[0][c].x = fmaf(zv0.z, w[c][k].z, acc[0][c].x);
                    acc[0][c].y = fmaf(zv0.w, w[c][k].w, acc[0][c].y);
                    acc[1][c].x = fmaf(zv1.x, w[c][k].x, acc[1][c].x);
                    acc[1][c].y = fmaf(zv1.y, w[c][k].y, acc[1][c].y);
                    acc[1][c].x = fmaf(zv1.z, w[c][k].z, acc[1][c].x);
                    acc[1][c].y = fmaf(zv1.w, w[c][k].w, acc[1][c].y);
                }
            }

            float ze[2][CD_];
            #pragma unroll
            for (int r = 0; r < 2; ++r) {
                #pragma unroll
                for (int c = 0; c < CD_; ++c) {
                    float v = acc[r][c].x + acc[r][c].y;
                    v = dpp_add<0xB1>(v);    // + lane^1
                    v = dpp_add<0x4E>(v);    // + lane^2
                    v = dpp_add<0x124>(v);   // + lane+4 (row_ror:4)
                    v = dpp_add<0x128>(v);   // + lane+8 (row_ror:8)
                    v += __shfl_xor(v, 16, 64);
                    v += __shfl_xor(v, 32, 64);
                    ze[r][c] = v + bia[c];
                }
            }

            if (lane == 0) {
                float4 p0 = make_float4(ze[0][0], ze[0][1], ze[0][2], ze[0][3]);
                float4 p1 = make_float4(ze[0][4], ze[0][5], ze[0][6], ze[0][7]);
                *(float4*)(dout + ZE_OFF + (size_t)row0 * CD_)     = p0;
                *(float4*)(dout + ZE_OFF + (size_t)row0 * CD_ + 4) = p1;
                *(float4*)(s_ze + lrow * CD_)     = p0;
                *(float4*)(s_ze + lrow * CD_ + 4) = p1;
            }
            if (lane == 1) {
                float4 p0 = make_float4(ze[1][0], ze[1][1], ze[1][2], ze[1][3]);
                float4 p1 = make_float4(ze[1][4], ze[1][5], ze[1][6], ze[1][7]);
                *(float4*)(dout + ZE_OFF + (size_t)(row0 + 1) * CD_)     = p0;
                *(float4*)(dout + ZE_OFF + (size_t)(row0 + 1) * CD_ + 4) = p1;
                *(float4*)(s_ze + (lrow + 1) * CD_)     = p0;
                *(float4*)(s_ze + (lrow + 1) * CD_ + 4) = p1;
            }
        }
    }
    __syncthreads();

    // ====== scan phase: 2 rows/thread (slot, slot+32), 8 subs, 0 conflicts =
    {
        int slot = t >> 3;        // 0..31
        int sub = t & 7;

        float4 a[2], b4[2];
        float tw[2];
        #pragma unroll
        for (int r = 0; r < 2; ++r) {
            int lrow = slot + (r << 5);
            a[r]  = *(const float4*)(s_ze + lrow * CD_);
            b4[r] = *(const float4*)(s_ze + lrow * CD_ + 4);
            float s = 0.f;
            s = fmaf(a[r].x, a[r].x, s);   s = fmaf(a[r].y, a[r].y, s);
            s = fmaf(a[r].z, a[r].z, s);   s = fmaf(a[r].w, a[r].w, s);
            s = fmaf(b4[r].x, b4[r].x, s); s = fmaf(b4[r].y, b4[r].y, s);
            s = fmaf(b4[r].z, b4[r].z, s); s = fmaf(b4[r].w, b4[r].w, s);
            tw[r] = 2.f / fmaxf(EPSF, sqrtf(s));
        }

        float bs[2] = {-1e38f, -1e38f};
        int   bj[2] = {0, 0};
        #pragma unroll 2
        for (int jj = 0; jj < 128; ++jj) {
            int j = (jj << 3) + sub;
            float4 ca  = ((const float4*)s_cb)[j * 2];
            float4 cbv = ((const float4*)s_cb)[j * 2 + 1];
            float c2 = s_c2[j];
            #pragma unroll
            for (int r = 0; r < 2; ++r) {
                float2 dp = make_float2(0.f, 0.f);
                dp.x = fmaf(ca.x,  a[r].x,  dp.x);
                dp.y = fmaf(ca.y,  a[r].y,  dp.y);
                dp.x = fmaf(ca.z,  a[r].z,  dp.x);
                dp.y = fmaf(ca.w,  a[r].w,  dp.y);
                dp.x = fmaf(cbv.x, b4[r].x, dp.x);
                dp.y = fmaf(cbv.y, b4[r].y, dp.y);
                dp.x = fmaf(cbv.z, b4[r].z, dp.x);
                dp.y = fmaf(cbv.w, b4[r].w, dp.y);
                float dot = dp.x + dp.y;
                float sc = fmaf(dot, tw[r], -c2);
                if (sc > bs[r] || (sc == bs[r] && j < bj[r])) { bs[r] = sc; bj[r] = j; }
            }
        }

        #pragma unroll
        for (int r = 0; r < 2; ++r) {
            #pragma unroll
            for (int m = 1; m <= 4; m <<= 1) {
                float os = __shfl_xor(bs[r], m, 64);
                int   oj = __shfl_xor(bj[r], m, 64);
                bool take = (os > bs[r]) || (os == bs[r] && oj < bj[r]);
                bs[r] = take ? os : bs[r];
                bj[r] = take ? oj : bj[r];
            }
        }

        float lsum = 0.f;
        if (sub == 0) {
            #pragma unroll
            for (int r = 0; r < 2; ++r) {
                int lrow = slot + (r << 5);
                int row = base + lrow;
                dout[IDX_OFF + row] = (float)bj[r];
                s_idx[lrow] = bj[r];
                const float* q = cb + (size_t)bj[r] * CD_;
                float d0 = a[r].x  - q[0]; lsum = fmaf(d0, d0, lsum);
                float d1 = a[r].y  - q[1]; lsum = fmaf(d1, d1, lsum);
                float d2 = a[r].z  - q[2]; lsum = fmaf(d2, d2, lsum);
                float d3 = a[r].w  - q[3]; lsum = fmaf(d3, d3, lsum);
                float d4 = b4[r].x - q[4]; lsum = fmaf(d4, d4, lsum);
                float d5 = b4[r].y - q[5]; lsum = fmaf(d5, d5, lsum);
                float d6 = b4[r].z - q[6]; lsum = fmaf(d6, d6, lsum);
                float d7 = b4[r].w - q[7]; lsum = fmaf(d7, d7, lsum);
            }
        }
        lsum += __shfl_xor(lsum, 1, 64);
        lsum += __shfl_xor(lsum, 2, 64);
        lsum += __shfl_xor(lsum, 4, 64);
        lsum += __shfl_xor(lsum, 8, 64);
        lsum += __shfl_xor(lsum, 16, 64);
        lsum += __shfl_xor(lsum, 32, 64);
        if (lane == 0) s_loss[wid] = lsum;
    }
    __syncthreads();
    if (t == 0) {
        float tot = s_loss[0] + s_loss[1] + s_loss[2] + s_loss[3];
        float v = tot * (1.f / 32768.f);
        int bt = base >> 12;
        atomicAdd(dout + COMMIT_OFF + bt, v);
        atomicAdd(dout + CBLOSS_OFF + bt, v);
    }

    // keep out-phase weight loads from hoisting into the ze phase
    __builtin_amdgcn_sched_barrier(0);

    // ================= out phase =================
    {
        float4 w[CD_][4];
        #pragma unroll
        for (int c = 0; c < CD_; ++c)
            #pragma unroll
            for (int k = 0; k < 4; ++k)
                w[c][k] = *(const float4*)(ws + WS_OUTW + c * D_ + (k << 8) + (lane << 2));

        float4 ob[4];
        #pragma unroll
        for (int k = 0; k < 4; ++k)
            ob[k] = *(const float4*)(out_b + (k << 8) + (lane << 2));

        #pragma unroll
        for (int itr = 0; itr < 4; ++itr) {
            int lr0 = (wid << 4) + (itr << 2);     // wave wid: rows wid*16 .. +15
            int row0 = base + lr0;

            float zq[4][CD_];
            #pragma unroll
            for (int r = 0; r < 4; ++r) {
                int j = s_idx[lr0 + r];
                #pragma unroll
                for (int c = 0; c < CD_; ++c) zq[r][c] = cb[j * CD_ + c];
            }

            #pragma unroll
            for (int k = 0; k < 4; ++k) {
                float4 a0 = ob[k], a1 = ob[k], a2 = ob[k], a3 = ob[k];
                #pragma unroll
                for (int c = 0; c < CD_; ++c) {
                    a0.x = fmaf(zq[0][c], w[c][k].x, a0.x); a0.y = fmaf(zq[0][c], w[c][k].y, a0.y);
                    a0.z = fmaf(zq[0][c], w[c][k].z, a0.z); a0.w = fmaf(zq[0][c], w[c][k].w, a0.w);
                    a1.x = fmaf(zq[1][c], w[c][k].x, a1.x); a1.y = fmaf(zq[1][c], w[c][k].y, a1.y);
                    a1.z = fmaf(zq[1][c], w[c][k].z, a1.z); a1.w = fmaf(zq[1][c], w[c][k].w, a1.w);
                    a2.x = fmaf(zq[2][c], w[c][k].x, a2.x); a2.y = fmaf(zq[2][c], w[c][k].y, a2.y);
                    a2.z = fmaf(zq[2][c], w[c][k].z, a2.z); a2.w = fmaf(zq[2][c], w[c][k].w, a2.w);
                    a3.x = fmaf(zq[3][c], w[c][k].x, a3.x); a3.y = fmaf(zq[3][c], w[c][k].y, a3.y);
                    a3.z = fmaf(zq[3][c], w[c][k].z, a3.z); a3.w = fmaf(zq[3][c], w[c][k].w, a3.w);
                }
                size_t baddr = (size_t)row0 * D_ + (k << 8) + (lane << 2);
                *(float4*)(dout + OUT_OFF + baddr)           = a0;
                *(float4*)(dout + OUT_OFF + baddr + D_)      = a1;
                *(float4*)(dout + OUT_OFF + baddr + 2 * D_)  = a2;
                *(float4*)(dout + OUT_OFF + baddr + 3 * D_)  = a3;
            }
        }
    }
}

extern "C" void kernel_launch(void* const* d_in, const int* in_sizes, int n_in,
                              void* d_out, int out_size, void* d_ws, size_t ws_size,
                              hipStream_t stream) {
    const float* z     = (const float*)d_in[0];
    const float* in_v  = (const float*)d_in[1];
    const float* in_g  = (const float*)d_in[2];
    const float* in_b  = (const float*)d_in[3];
    const float* out_v = (const float*)d_in[4];
    const float* out_g = (const float*)d_in[5];
    const float* out_b = (const float*)d_in[6];
    const float* cb    = (const float*)d_in[7];
    float* dout = (float*)d_out;
    float* ws   = (float*)d_ws;

    vq_prep<<<24, 256, 0, stream>>>(in_v, in_g, out_v, out_g, cb, ws, dout);
    vq_fused<<<1024, 256, 0, stream>>>(z, in_b, cb, ws, out_b, dout);
}